// Round 8
// baseline (239.062 us; speedup 1.0000x reference)
//
#include <hip/hip_runtime.h>
#include <hip/hip_bf16.h>

#define NB 8
#define NN 256
#define DIMV 256
#define DI 64
#define NEGMAX 3.402823466e+38f

typedef unsigned short u16;
typedef unsigned int u32;
typedef __attribute__((ext_vector_type(8))) short bf16x8;
typedef __attribute__((ext_vector_type(4))) float f32x4;
typedef __attribute__((ext_vector_type(2))) float f32x2;
typedef __attribute__((ext_vector_type(2))) unsigned int u32x2;

__device__ __forceinline__ u16 f2bf(float f) {
    __hip_bfloat16 h = __float2bfloat16(f);
    u16 u; __builtin_memcpy(&u, &h, 2); return u;
}
__device__ __forceinline__ u32 pack2(float a, float b) {
    return (u32)f2bf(a) | ((u32)f2bf(b) << 16);
}
__device__ __forceinline__ float ubf_lo(u32 u) {
    union { u32 u; float f; } x; x.u = u << 16; return x.f;
}
__device__ __forceinline__ float ubf_hi(u32 u) {
    union { u32 u; float f; } x; x.u = u & 0xffff0000u; return x.f;
}
// swizzles: fA for 128B-stride rows, fB for 64B-stride rows (bits 4-6 only)
__device__ __forceinline__ int fA(int row) { return ((row & 7) << 4) ^ ((row & 8) << 2); }
__device__ __forceinline__ int fB(int row) { return ((row >> 1) & 7) << 4; }

// ---------------------------------------------------------------------------
__global__ void prep_w(const float* __restrict__ w1, const float* __restrict__ w2,
                       const float* __restrict__ pw2,
                       u16* __restrict__ w1t, u16* __restrict__ w2t, u16* __restrict__ pw2t)
{
    int idx = blockIdx.x * 256 + threadIdx.x;
    if (idx < 16384) {
        { int o = idx >> 6, kk = idx & 63;  w1t[idx] = f2bf(w1[kk * 256 + o]); }
        { int d = idx >> 8, h  = idx & 255; w2t[idx] = f2bf(w2[h * 64 + d]); }
    }
    if (idx < 4096) { int d = idx >> 6, h = idx & 63; pw2t[idx] = f2bf(pw2[h * 64 + d]); }
}

// ---------------------------------------------------------------------------
__global__ void prep_qkv(const float* __restrict__ x, const float* __restrict__ y,
                         const float* __restrict__ tw, const float* __restrict__ pw,
                         const float* __restrict__ gw,
                         float* __restrict__ q, float* __restrict__ k, float* __restrict__ v)
{
    __shared__ float xs[4][256];
    __shared__ float ys[4][256];
    const int blk = blockIdx.x;
    const int b = blk >> 6;
    const int n0 = (blk & 63) * 4;
    const int tid = threadIdx.x;
    {
        int r = tid >> 6, e = tid & 63;
        ((float4*)xs[r])[e] = ((const float4*)(x + (size_t)(b * NN + n0 + r) * DIMV))[e];
        ((float4*)ys[r])[e] = ((const float4*)(y + (size_t)(b * NN + n0 + r) * DIMV))[e];
    }
    __syncthreads();
    const int nl = tid >> 6, d = tid & 63;
    float aq = 0.f, ak = 0.f, av = 0.f;
    #pragma unroll 4
    for (int c = 0; c < 256; ++c) {
        float wq = tw[c * 64 + d], wk = pw[c * 64 + d], wv = gw[c * 64 + d];
        float xv = xs[nl][c], yv = ys[nl][c];
        aq += xv * wq; ak += yv * wk; av += yv * wv;
    }
    const int n = n0 + nl;
    q[(b * NN + n) * DI + d] = aq;
    k[(b * NN + n) * DI + d] = ak;
    v[(b * NN + n) * DI + d] = av;
}

// ---------------------------------------------------------------------------
// one block per (b, i); 512 threads = 8 waves; wave w owns 32 j-rows
// [w*32, w*32+32) as 2 row-tiles.  Halved per-wave accumulators (accS 32,
// aT 16, v_full 16 regs) keep combined VGPR+AGPR <= 128 -> 4 waves/SIMD
// (r1-r7 were stuck at 2 waves/SIMD: 64-row waves need ~190 combined regs;
// rocprof VGPR_Count excludes AGPRs).  LDS 32 KB: per-wave 4 KB stage/Hc
// double-buffer; softmax reductions overlay post-barrier.
// __launch_bounds__(512,4): VGPR cap 128 (cap = B/n rule, r2/r5/r6-verified).
// ---------------------------------------------------------------------------
__global__ __launch_bounds__(512, 4)
void fused_attn(const float* __restrict__ x, const float* __restrict__ x_pos,
                const float* __restrict__ y_pos, const int* __restrict__ mask,
                const float* __restrict__ pw1, const float* __restrict__ pb1,
                const float* __restrict__ pb2,
                const float* __restrict__ ab1, const float* __restrict__ ab2,
                const float* __restrict__ out_w,
                const float* __restrict__ qg, const float* __restrict__ kg,
                const float* __restrict__ vg,
                const u16* __restrict__ w1t, const u16* __restrict__ w2t,
                const u16* __restrict__ pw2t,
                float* __restrict__ out)
{
    __shared__ __align__(16) char sStg[8][4096];   // 32 KB: stage/Hc dbuf per wave

    const int blk = blockIdx.x;
    const int b = blk >> 8;
    const int i = blk & 255;
    const int tid = threadIdx.x;
    const int l   = tid & 63;
    const int w   = tid >> 6;          // 0..7
    const int j0  = w * 32;
    const int l15 = l & 15;
    const int lh  = l >> 4;

    char* const stg  = sStg[w];        // 4 KB: [0,2K) stage/buf0, [2K,4K) buf1
    float* const sRedF = (float*)&sStg[0][0];      // overlay, post-barrier only

    // hoisted LDS addresses (row-local within a 16-row tile)
    int stW[4], hcW[4];
    #pragma unroll
    for (int r = 0; r < 4; ++r) {
        const int lr = lh * 4 + r;
        stW[r] = (lr * 128 + l15 * 8) ^ fA(lr);    // T-stage write
        hcW[r] = (lr * 64 + l15 * 4) ^ fB(lr);     // Hc write (+rt*1024)
    }
    const int stR0 = (l15 * 128 + lh * 16) ^ fA(l15);
    const int stR1 = stR0 ^ 64;
    const int hcR  = (l15 * 64 + lh * 16) ^ fB(l15);

    // ---- mask: wave's 32 rows come from lanes 0..31's ballot bits ----
    const int mjl = mask[b * NN + j0 + (l & 31)];
    const unsigned long long mb = __ballot(mjl != 0);
    const bool mi_b = mask[b * NN + i] != 0;

    // ---- phase 0: pos-MLP layer 1 into GEMM0 A-fragments ----
    const float xp0 = x_pos[(b * NN + i) * 3 + 0];
    const float xp1 = x_pos[(b * NN + i) * 3 + 1];
    const float xp2 = x_pos[(b * NN + i) * 3 + 2];

    bf16x8 af[2][2];
    {
        float rel[2][3];
        #pragma unroll
        for (int rt = 0; rt < 2; ++rt) {
            const float* yp = y_pos + (size_t)(b * NN + j0 + rt * 16 + l15) * 3;
            rel[rt][0] = xp0 - yp[0];
            rel[rt][1] = xp1 - yp[1];
            rel[rt][2] = xp2 - yp[2];
        }
        #pragma unroll
        for (int ks = 0; ks < 2; ++ks) {
            const int c0 = ks * 32 + lh * 8;
            float w0[8], w1c[8], w2c[8], bb[8];
            #pragma unroll
            for (int qq = 0; qq < 2; ++qq) {
                *(f32x4*)&w0[qq*4]  = *(const f32x4*)&pw1[0*64 + c0 + qq*4];
                *(f32x4*)&w1c[qq*4] = *(const f32x4*)&pw1[1*64 + c0 + qq*4];
                *(f32x4*)&w2c[qq*4] = *(const f32x4*)&pw1[2*64 + c0 + qq*4];
                *(f32x4*)&bb[qq*4]  = *(const f32x4*)&pb1[c0 + qq*4];
            }
            #pragma unroll
            for (int rt = 0; rt < 2; ++rt) {
                bf16x8 v;
                #pragma unroll
                for (int cc = 0; cc < 8; ++cc) {
                    float h = bb[cc] + rel[rt][0]*w0[cc] + rel[rt][1]*w1c[cc] + rel[rt][2]*w2c[cc];
                    v[cc] = (short)f2bf(fmaxf(h, 0.f));
                }
                af[rt][ks] = v;
            }
        }
    }

    // ---- GEMM0 + epilogue per rt; aT hoist; v_full fully in regs ----
    const f32x4 qv   = *(const f32x4*)&qg[((size_t)b * NN + i) * DI + 4 * l15];
    const f32x4 pb2v = *(const f32x4*)&pb2[4 * l15];

    bf16x8 aT[2][2];
    u32x2 accVp[2][4];
    #pragma unroll
    for (int rt = 0; rt < 2; ++rt) {
        f32x4 accR[4];
        #pragma unroll
        for (int ct = 0; ct < 4; ++ct) {
            bf16x8 bfr0 = *(const bf16x8*)(pw2t + (4 * l15 + ct) * 64 + lh * 8);
            bf16x8 bfr1 = *(const bf16x8*)(pw2t + (4 * l15 + ct) * 64 + 32 + lh * 8);
            f32x4 a = {pb2v[ct], pb2v[ct], pb2v[ct], pb2v[ct]};   // pb2 folded
            a = __builtin_amdgcn_mfma_f32_16x16x32_bf16(af[rt][0], bfr0, a, 0, 0, 0);
            a = __builtin_amdgcn_mfma_f32_16x16x32_bf16(af[rt][1], bfr1, a, 0, 0, 0);
            accR[ct] = a;
        }
        #pragma unroll
        for (int r = 0; r < 4; ++r) {
            const int row = j0 + rt * 16 + lh * 4 + r;
            const f32x4 kv = *(const f32x4*)&kg[((size_t)b * NN + row) * DI + 4 * l15];
            const f32x4 vv = *(const f32x4*)&vg[((size_t)b * NN + row) * DI + 4 * l15];
            float tv[4], vf[4];
            #pragma unroll
            for (int ct = 0; ct < 4; ++ct) {
                const float rpe = accR[ct][r];
                tv[ct] = qv[ct] - kv[ct] + rpe;
                vf[ct] = vv[ct] + rpe;
            }
            u32x2 tpk; tpk[0] = pack2(tv[0], tv[1]); tpk[1] = pack2(tv[2], tv[3]);
            accVp[rt][r][0] = pack2(vf[0], vf[1]);
            accVp[rt][r][1] = pack2(vf[2], vf[3]);
            *(u32x2*)(stg + stW[r]) = tpk;
        }
        aT[rt][0] = *(const bf16x8*)(stg + stR0);
        aT[rt][1] = *(const bf16x8*)(stg + stR1);
    }

    // ---- chunk loop: 8 chunks of 32 hidden; Hc double-buffered; SIM in regs ----
    const f32x4 ab2v = *(const f32x4*)&ab2[4 * l15];
    f32x4 accS[2][4];
    #pragma unroll
    for (int rt = 0; rt < 2; ++rt)
        #pragma unroll
        for (int ct = 0; ct < 4; ++ct)
            accS[rt][ct] = (f32x4){ab2v[ct], ab2v[ct], ab2v[ct], ab2v[ct]};  // ab2 folded

    #pragma unroll 1
    for (int hc = 0; hc < 8; ++hc) {
        char* const buf = stg + ((hc & 1) ? 2048 : 0);
        // GEMM1 -> Hc chunk
        bf16x8 b1f[2][2];
        #pragma unroll
        for (int c2 = 0; c2 < 2; ++c2)
            #pragma unroll
            for (int ks = 0; ks < 2; ++ks) {
                const int hid = hc * 32 + 2 * l15 + c2;
                b1f[c2][ks] = *(const bf16x8*)(w1t + hid * 64 + ks * 32 + lh * 8);
            }
        const f32x2 ab1v = *(const f32x2*)&ab1[hc * 32 + 2 * l15];
        const f32x4 ib0 = {ab1v[0], ab1v[0], ab1v[0], ab1v[0]};
        const f32x4 ib1 = {ab1v[1], ab1v[1], ab1v[1], ab1v[1]};
        #pragma unroll
        for (int rt = 0; rt < 2; ++rt) {
            f32x4 h0 = ib0, h1 = ib1;                  // ab1 folded
            h0 = __builtin_amdgcn_mfma_f32_16x16x32_bf16(aT[rt][0], b1f[0][0], h0, 0, 0, 0);
            h0 = __builtin_amdgcn_mfma_f32_16x16x32_bf16(aT[rt][1], b1f[0][1], h0, 0, 0, 0);
            h1 = __builtin_amdgcn_mfma_f32_16x16x32_bf16(aT[rt][0], b1f[1][0], h1, 0, 0, 0);
            h1 = __builtin_amdgcn_mfma_f32_16x16x32_bf16(aT[rt][1], b1f[1][1], h1, 0, 0, 0);
            #pragma unroll
            for (int r = 0; r < 4; ++r)
                *(u32*)(buf + hcW[r] + rt * 1024) =
                    pack2(fmaxf(h0[r], 0.f), fmaxf(h1[r], 0.f));
        }
        // GEMM2: Hc @ W2[chunk,:]
        bf16x8 a2[2];
        a2[0] = *(const bf16x8*)(buf + hcR);
        a2[1] = *(const bf16x8*)(buf + hcR + 1024);
        #pragma unroll
        for (int ct = 0; ct < 4; ++ct) {
            bf16x8 b2f = *(const bf16x8*)(w2t + (4 * l15 + ct) * 256 + hc * 32 + lh * 8);
            #pragma unroll
            for (int rt = 0; rt < 2; ++rt)
                accS[rt][ct] = __builtin_amdgcn_mfma_f32_16x16x32_bf16(a2[rt], b2f, accS[rt][ct], 0, 0, 0);
        }
    }

    // ---- softmax: in-register; wave-local max over 32 rows ----
    float mx[4] = {-NEGMAX, -NEGMAX, -NEGMAX, -NEGMAX};
    #pragma unroll
    for (int rt = 0; rt < 2; ++rt)
        #pragma unroll
        for (int r = 0; r < 4; ++r) {
            const int ro = rt * 16 + lh * 4 + r;        // 0..31
            const bool bit = mi_b && ((mb >> ro) & 1ull);
            #pragma unroll
            for (int ct = 0; ct < 4; ++ct) {
                float s = bit ? accS[rt][ct][r] : -NEGMAX;
                accS[rt][ct][r] = s;
                mx[ct] = fmaxf(mx[ct], s);
            }
        }
    #pragma unroll
    for (int ct = 0; ct < 4; ++ct) {
        mx[ct] = fmaxf(mx[ct], __shfl_xor(mx[ct], 16));
        mx[ct] = fmaxf(mx[ct], __shfl_xor(mx[ct], 32));
    }
    __syncthreads();                    // stage/Hc dead -> sRed overlay OK
    if (lh == 0)
        *(f32x4*)&sRedF[w * 64 + 4 * l15] = (f32x4){mx[0], mx[1], mx[2], mx[3]};
    __syncthreads();
    float m4[4];
    {
        f32x4 a0 = *(f32x4*)&sRedF[4 * l15];
        #pragma unroll
        for (int ct = 0; ct < 4; ++ct) m4[ct] = a0[ct];
        #pragma unroll
        for (int wv = 1; wv < 8; ++wv) {
            f32x4 aw = *(f32x4*)&sRedF[wv * 64 + 4 * l15];
            #pragma unroll
            for (int ct = 0; ct < 4; ++ct) m4[ct] = fmaxf(m4[ct], aw[ct]);
        }
    }
    float ssum[4] = {0.f, 0.f, 0.f, 0.f}, sagg[4] = {0.f, 0.f, 0.f, 0.f};
    #pragma unroll
    for (int rt = 0; rt < 2; ++rt)
        #pragma unroll
        for (int r = 0; r < 4; ++r) {
            const u32x2 vpk = accVp[rt][r];
            const float vfs[4] = {ubf_lo(vpk[0]), ubf_hi(vpk[0]), ubf_lo(vpk[1]), ubf_hi(vpk[1])};
            #pragma unroll
            for (int ct = 0; ct < 4; ++ct) {
                const float e = __expf(accS[rt][ct][r] - m4[ct]);
                ssum[ct] += e;
                sagg[ct] += e * vfs[ct];
            }
        }
    #pragma unroll
    for (int ct = 0; ct < 4; ++ct) {
        ssum[ct] += __shfl_xor(ssum[ct], 16);
        ssum[ct] += __shfl_xor(ssum[ct], 32);
        sagg[ct] += __shfl_xor(sagg[ct], 16);
        sagg[ct] += __shfl_xor(sagg[ct], 32);
    }
    if (lh == 0) {
        *(f32x4*)&sRedF[512 + w * 64 + 4 * l15]  = (f32x4){ssum[0], ssum[1], ssum[2], ssum[3]};
        *(f32x4*)&sRedF[1024 + w * 64 + 4 * l15] = (f32x4){sagg[0], sagg[1], sagg[2], sagg[3]};
    }
    __syncthreads();
    if (tid < 64) {
        float den = 0.f, ag = 0.f;
        #pragma unroll
        for (int wv = 0; wv < 8; ++wv) {
            den += sRedF[512 + wv * 64 + tid];
            ag  += sRedF[1024 + wv * 64 + tid];
        }
        sRedF[1536 + tid] = ag / den;
    }
    __syncthreads();

    // ---- out[i,:] = x[i,:] + agg @ out_w (threads 0..255) ----
    if (tid < DIMV) {
        float acc = 0.f;
        #pragma unroll 8
        for (int d = 0; d < 64; ++d)
            acc += sRedF[1536 + d] * out_w[d * DIMV + tid];
        const int o = (b * NN + i) * DIMV + tid;
        out[o] = x[o] + acc;
    }
}

// ---------------------------------------------------------------------------
extern "C" void kernel_launch(void* const* d_in, const int* in_sizes, int n_in,
                              void* d_out, int out_size, void* d_ws, size_t ws_size,
                              hipStream_t stream)
{
    const float* x       = (const float*)d_in[0];
    const float* y       = (const float*)d_in[1];
    const float* x_pos   = (const float*)d_in[2];
    const float* y_pos   = (const float*)d_in[3];
    const int*   mask    = (const int*)d_in[4];
    const float* g_w     = (const float*)d_in[5];
    const float* theta_w = (const float*)d_in[6];
    const float* phi_w   = (const float*)d_in[7];
    const float* pos_w1  = (const float*)d_in[8];
    const float* pos_b1  = (const float*)d_in[9];
    const float* pos_w2  = (const float*)d_in[10];
    const float* pos_b2  = (const float*)d_in[11];
    const float* attn_w1 = (const float*)d_in[12];
    const float* attn_b1 = (const float*)d_in[13];
    const float* attn_w2 = (const float*)d_in[14];
    const float* attn_b2 = (const float*)d_in[15];
    const float* out_w   = (const float*)d_in[16];

    float* q = (float*)d_ws;
    float* k = q + NB * NN * DI;
    float* v = k + NB * NN * DI;
    u16* w1t  = (u16*)(v + NB * NN * DI);   // 256*64
    u16* w2t  = w1t + 256 * 64;             // 64*256
    u16* pw2t = w2t + 64 * 256;             // 64*64

    prep_w<<<64, 256, 0, stream>>>(attn_w1, attn_w2, pos_w2, w1t, w2t, pw2t);
    prep_qkv<<<512, 256, 0, stream>>>(x, y, theta_w, phi_w, g_w, q, k, v);
    fused_attn<<<NB * NN, 512, 0, stream>>>(x, x_pos, y_pos, mask,
                                            pos_w1, pos_b1, pos_b2,
                                            attn_b1, attn_b2, out_w,
                                            q, k, v, w1t, w2t, pw2t,
                                            (float*)d_out);
}

// Round 9
// 210.801 us; speedup vs baseline: 1.1341x; 1.1341x over previous
//
#include <hip/hip_runtime.h>
#include <hip/hip_bf16.h>

#define NB 8
#define NN 256
#define DIMV 256
#define DI 64
#define NEGMAX 3.402823466e+38f

typedef unsigned short u16;
typedef unsigned int u32;
typedef __attribute__((ext_vector_type(8))) short bf16x8;
typedef __attribute__((ext_vector_type(4))) float f32x4;
typedef __attribute__((ext_vector_type(2))) float f32x2;
typedef __attribute__((ext_vector_type(2))) unsigned int u32x2;

__device__ __forceinline__ u16 f2bf(float f) {
    __hip_bfloat16 h = __float2bfloat16(f);
    u16 u; __builtin_memcpy(&u, &h, 2); return u;
}
__device__ __forceinline__ u32 pack2(float a, float b) {
    return (u32)f2bf(a) | ((u32)f2bf(b) << 16);
}
__device__ __forceinline__ float ubf_lo(u32 u) {
    union { u32 u; float f; } x; x.u = u << 16; return x.f;
}
__device__ __forceinline__ float ubf_hi(u32 u) {
    union { u32 u; float f; } x; x.u = u & 0xffff0000u; return x.f;
}
// swizzles: fA for 128B-stride rows, fB for 64B-stride rows (bits 4-6 only)
__device__ __forceinline__ int fA(int row) { return ((row & 7) << 4) ^ ((row & 8) << 2); }
__device__ __forceinline__ int fB(int row) { return ((row >> 1) & 7) << 4; }

// ---------------------------------------------------------------------------
__global__ void prep_w(const float* __restrict__ w1, const float* __restrict__ w2,
                       const float* __restrict__ pw2,
                       u16* __restrict__ w1t, u16* __restrict__ w2t, u16* __restrict__ pw2t)
{
    int idx = blockIdx.x * 256 + threadIdx.x;
    if (idx < 16384) {
        { int o = idx >> 6, kk = idx & 63;  w1t[idx] = f2bf(w1[kk * 256 + o]); }
        { int d = idx >> 8, h  = idx & 255; w2t[idx] = f2bf(w2[h * 64 + d]); }
    }
    if (idx < 4096) { int d = idx >> 6, h = idx & 63; pw2t[idx] = f2bf(pw2[h * 64 + d]); }
}

// ---------------------------------------------------------------------------
__global__ void prep_qkv(const float* __restrict__ x, const float* __restrict__ y,
                         const float* __restrict__ tw, const float* __restrict__ pw,
                         const float* __restrict__ gw,
                         float* __restrict__ q, float* __restrict__ k, float* __restrict__ v)
{
    __shared__ float xs[4][256];
    __shared__ float ys[4][256];
    const int blk = blockIdx.x;
    const int b = blk >> 6;
    const int n0 = (blk & 63) * 4;
    const int tid = threadIdx.x;
    {
        int r = tid >> 6, e = tid & 63;
        ((float4*)xs[r])[e] = ((const float4*)(x + (size_t)(b * NN + n0 + r) * DIMV))[e];
        ((float4*)ys[r])[e] = ((const float4*)(y + (size_t)(b * NN + n0 + r) * DIMV))[e];
    }
    __syncthreads();
    const int nl = tid >> 6, d = tid & 63;
    float aq = 0.f, ak = 0.f, av = 0.f;
    #pragma unroll 4
    for (int c = 0; c < 256; ++c) {
        float wq = tw[c * 64 + d], wk = pw[c * 64 + d], wv = gw[c * 64 + d];
        float xv = xs[nl][c], yv = ys[nl][c];
        aq += xv * wq; ak += yv * wk; av += yv * wv;
    }
    const int n = n0 + nl;
    q[(b * NN + n) * DI + d] = aq;
    k[(b * NN + n) * DI + d] = ak;
    v[(b * NN + n) * DI + d] = av;
}

// ---------------------------------------------------------------------------
// one block per (b, i); 512 threads = 8 waves; wave w owns 32 j-rows
// [w*32, w*32+32) as 2 row-tiles.  Halved per-wave accumulators (accS 32,
// aT 16, v_full 16 regs) -> live set ~110-125.
// __launch_bounds__(512,2): VGPR cap 128.  Empirical cap rule (r2/r5/r6/r8):
// cap = 256/min_waves REGARDLESS of block size — (512,4) gave 64 and spilled
// (r8: FETCH 92MB), (256,2)/(512,2) give 128 which fits this live set (r7).
// r8 proved the 8-wave structure doubles occupancy (44% even while spilling).
// LDS 32 KB: per-wave 4 KB stage/Hc dbuf; reductions overlay post-barrier.
// ---------------------------------------------------------------------------
__global__ __launch_bounds__(512, 2)
void fused_attn(const float* __restrict__ x, const float* __restrict__ x_pos,
                const float* __restrict__ y_pos, const int* __restrict__ mask,
                const float* __restrict__ pw1, const float* __restrict__ pb1,
                const float* __restrict__ pb2,
                const float* __restrict__ ab1, const float* __restrict__ ab2,
                const float* __restrict__ out_w,
                const float* __restrict__ qg, const float* __restrict__ kg,
                const float* __restrict__ vg,
                const u16* __restrict__ w1t, const u16* __restrict__ w2t,
                const u16* __restrict__ pw2t,
                float* __restrict__ out)
{
    __shared__ __align__(16) char sStg[8][4096];   // 32 KB: stage/Hc dbuf per wave

    const int blk = blockIdx.x;
    const int b = blk >> 8;
    const int i = blk & 255;
    const int tid = threadIdx.x;
    const int l   = tid & 63;
    const int w   = tid >> 6;          // 0..7
    const int j0  = w * 32;
    const int l15 = l & 15;
    const int lh  = l >> 4;

    char* const stg  = sStg[w];        // 4 KB: [0,2K) stage/buf0, [2K,4K) buf1
    float* const sRedF = (float*)&sStg[0][0];      // overlay, post-barrier only

    // hoisted LDS addresses (row-local within a 16-row tile)
    int stW[4], hcW[4];
    #pragma unroll
    for (int r = 0; r < 4; ++r) {
        const int lr = lh * 4 + r;
        stW[r] = (lr * 128 + l15 * 8) ^ fA(lr);    // T-stage write
        hcW[r] = (lr * 64 + l15 * 4) ^ fB(lr);     // Hc write (+rt*1024)
    }
    const int stR0 = (l15 * 128 + lh * 16) ^ fA(l15);
    const int stR1 = stR0 ^ 64;
    const int hcR  = (l15 * 64 + lh * 16) ^ fB(l15);

    // ---- mask: wave's 32 rows come from lanes 0..31's ballot bits ----
    const int mjl = mask[b * NN + j0 + (l & 31)];
    const unsigned long long mb = __ballot(mjl != 0);
    const bool mi_b = mask[b * NN + i] != 0;

    // ---- phase 0: pos-MLP layer 1 into GEMM0 A-fragments ----
    const float xp0 = x_pos[(b * NN + i) * 3 + 0];
    const float xp1 = x_pos[(b * NN + i) * 3 + 1];
    const float xp2 = x_pos[(b * NN + i) * 3 + 2];

    bf16x8 af[2][2];
    {
        float rel[2][3];
        #pragma unroll
        for (int rt = 0; rt < 2; ++rt) {
            const float* yp = y_pos + (size_t)(b * NN + j0 + rt * 16 + l15) * 3;
            rel[rt][0] = xp0 - yp[0];
            rel[rt][1] = xp1 - yp[1];
            rel[rt][2] = xp2 - yp[2];
        }
        #pragma unroll
        for (int ks = 0; ks < 2; ++ks) {
            const int c0 = ks * 32 + lh * 8;
            float w0[8], w1c[8], w2c[8], bb[8];
            #pragma unroll
            for (int qq = 0; qq < 2; ++qq) {
                *(f32x4*)&w0[qq*4]  = *(const f32x4*)&pw1[0*64 + c0 + qq*4];
                *(f32x4*)&w1c[qq*4] = *(const f32x4*)&pw1[1*64 + c0 + qq*4];
                *(f32x4*)&w2c[qq*4] = *(const f32x4*)&pw1[2*64 + c0 + qq*4];
                *(f32x4*)&bb[qq*4]  = *(const f32x4*)&pb1[c0 + qq*4];
            }
            #pragma unroll
            for (int rt = 0; rt < 2; ++rt) {
                bf16x8 v;
                #pragma unroll
                for (int cc = 0; cc < 8; ++cc) {
                    float h = bb[cc] + rel[rt][0]*w0[cc] + rel[rt][1]*w1c[cc] + rel[rt][2]*w2c[cc];
                    v[cc] = (short)f2bf(fmaxf(h, 0.f));
                }
                af[rt][ks] = v;
            }
        }
    }

    // ---- GEMM0 + epilogue per rt; aT hoist; v_full fully in regs ----
    const f32x4 qv   = *(const f32x4*)&qg[((size_t)b * NN + i) * DI + 4 * l15];
    const f32x4 pb2v = *(const f32x4*)&pb2[4 * l15];

    bf16x8 aT[2][2];
    u32x2 accVp[2][4];
    #pragma unroll
    for (int rt = 0; rt < 2; ++rt) {
        f32x4 accR[4];
        #pragma unroll
        for (int ct = 0; ct < 4; ++ct) {
            bf16x8 bfr0 = *(const bf16x8*)(pw2t + (4 * l15 + ct) * 64 + lh * 8);
            bf16x8 bfr1 = *(const bf16x8*)(pw2t + (4 * l15 + ct) * 64 + 32 + lh * 8);
            f32x4 a = {pb2v[ct], pb2v[ct], pb2v[ct], pb2v[ct]};   // pb2 folded
            a = __builtin_amdgcn_mfma_f32_16x16x32_bf16(af[rt][0], bfr0, a, 0, 0, 0);
            a = __builtin_amdgcn_mfma_f32_16x16x32_bf16(af[rt][1], bfr1, a, 0, 0, 0);
            accR[ct] = a;
        }
        #pragma unroll
        for (int r = 0; r < 4; ++r) {
            const int row = j0 + rt * 16 + lh * 4 + r;
            const f32x4 kv = *(const f32x4*)&kg[((size_t)b * NN + row) * DI + 4 * l15];
            const f32x4 vv = *(const f32x4*)&vg[((size_t)b * NN + row) * DI + 4 * l15];
            float tv[4], vf[4];
            #pragma unroll
            for (int ct = 0; ct < 4; ++ct) {
                const float rpe = accR[ct][r];
                tv[ct] = qv[ct] - kv[ct] + rpe;
                vf[ct] = vv[ct] + rpe;
            }
            u32x2 tpk; tpk[0] = pack2(tv[0], tv[1]); tpk[1] = pack2(tv[2], tv[3]);
            accVp[rt][r][0] = pack2(vf[0], vf[1]);
            accVp[rt][r][1] = pack2(vf[2], vf[3]);
            *(u32x2*)(stg + stW[r]) = tpk;
        }
        aT[rt][0] = *(const bf16x8*)(stg + stR0);
        aT[rt][1] = *(const bf16x8*)(stg + stR1);
    }

    // ---- chunk loop: 8 chunks of 32 hidden; Hc double-buffered; SIM in regs ----
    const f32x4 ab2v = *(const f32x4*)&ab2[4 * l15];
    f32x4 accS[2][4];
    #pragma unroll
    for (int rt = 0; rt < 2; ++rt)
        #pragma unroll
        for (int ct = 0; ct < 4; ++ct)
            accS[rt][ct] = (f32x4){ab2v[ct], ab2v[ct], ab2v[ct], ab2v[ct]};  // ab2 folded

    #pragma unroll 1
    for (int hc = 0; hc < 8; ++hc) {
        char* const buf = stg + ((hc & 1) ? 2048 : 0);
        // GEMM1 -> Hc chunk
        bf16x8 b1f[2][2];
        #pragma unroll
        for (int c2 = 0; c2 < 2; ++c2)
            #pragma unroll
            for (int ks = 0; ks < 2; ++ks) {
                const int hid = hc * 32 + 2 * l15 + c2;
                b1f[c2][ks] = *(const bf16x8*)(w1t + hid * 64 + ks * 32 + lh * 8);
            }
        const f32x2 ab1v = *(const f32x2*)&ab1[hc * 32 + 2 * l15];
        const f32x4 ib0 = {ab1v[0], ab1v[0], ab1v[0], ab1v[0]};
        const f32x4 ib1 = {ab1v[1], ab1v[1], ab1v[1], ab1v[1]};
        #pragma unroll
        for (int rt = 0; rt < 2; ++rt) {
            f32x4 h0 = ib0, h1 = ib1;                  // ab1 folded
            h0 = __builtin_amdgcn_mfma_f32_16x16x32_bf16(aT[rt][0], b1f[0][0], h0, 0, 0, 0);
            h0 = __builtin_amdgcn_mfma_f32_16x16x32_bf16(aT[rt][1], b1f[0][1], h0, 0, 0, 0);
            h1 = __builtin_amdgcn_mfma_f32_16x16x32_bf16(aT[rt][0], b1f[1][0], h1, 0, 0, 0);
            h1 = __builtin_amdgcn_mfma_f32_16x16x32_bf16(aT[rt][1], b1f[1][1], h1, 0, 0, 0);
            #pragma unroll
            for (int r = 0; r < 4; ++r)
                *(u32*)(buf + hcW[r] + rt * 1024) =
                    pack2(fmaxf(h0[r], 0.f), fmaxf(h1[r], 0.f));
        }
        // GEMM2: Hc @ W2[chunk,:]
        bf16x8 a2[2];
        a2[0] = *(const bf16x8*)(buf + hcR);
        a2[1] = *(const bf16x8*)(buf + hcR + 1024);
        #pragma unroll
        for (int ct = 0; ct < 4; ++ct) {
            bf16x8 b2f = *(const bf16x8*)(w2t + (4 * l15 + ct) * 256 + hc * 32 + lh * 8);
            #pragma unroll
            for (int rt = 0; rt < 2; ++rt)
                accS[rt][ct] = __builtin_amdgcn_mfma_f32_16x16x32_bf16(a2[rt], b2f, accS[rt][ct], 0, 0, 0);
        }
    }

    // ---- softmax: in-register; wave-local max over 32 rows ----
    float mx[4] = {-NEGMAX, -NEGMAX, -NEGMAX, -NEGMAX};
    #pragma unroll
    for (int rt = 0; rt < 2; ++rt)
        #pragma unroll
        for (int r = 0; r < 4; ++r) {
            const int ro = rt * 16 + lh * 4 + r;        // 0..31
            const bool bit = mi_b && ((mb >> ro) & 1ull);
            #pragma unroll
            for (int ct = 0; ct < 4; ++ct) {
                float s = bit ? accS[rt][ct][r] : -NEGMAX;
                accS[rt][ct][r] = s;
                mx[ct] = fmaxf(mx[ct], s);
            }
        }
    #pragma unroll
    for (int ct = 0; ct < 4; ++ct) {
        mx[ct] = fmaxf(mx[ct], __shfl_xor(mx[ct], 16));
        mx[ct] = fmaxf(mx[ct], __shfl_xor(mx[ct], 32));
    }
    __syncthreads();                    // stage/Hc dead -> sRed overlay OK
    if (lh == 0)
        *(f32x4*)&sRedF[w * 64 + 4 * l15] = (f32x4){mx[0], mx[1], mx[2], mx[3]};
    __syncthreads();
    float m4[4];
    {
        f32x4 a0 = *(f32x4*)&sRedF[4 * l15];
        #pragma unroll
        for (int ct = 0; ct < 4; ++ct) m4[ct] = a0[ct];
        #pragma unroll
        for (int wv = 1; wv < 8; ++wv) {
            f32x4 aw = *(f32x4*)&sRedF[wv * 64 + 4 * l15];
            #pragma unroll
            for (int ct = 0; ct < 4; ++ct) m4[ct] = fmaxf(m4[ct], aw[ct]);
        }
    }
    float ssum[4] = {0.f, 0.f, 0.f, 0.f}, sagg[4] = {0.f, 0.f, 0.f, 0.f};
    #pragma unroll
    for (int rt = 0; rt < 2; ++rt)
        #pragma unroll
        for (int r = 0; r < 4; ++r) {
            const u32x2 vpk = accVp[rt][r];
            const float vfs[4] = {ubf_lo(vpk[0]), ubf_hi(vpk[0]), ubf_lo(vpk[1]), ubf_hi(vpk[1])};
            #pragma unroll
            for (int ct = 0; ct < 4; ++ct) {
                const float e = __expf(accS[rt][ct][r] - m4[ct]);
                ssum[ct] += e;
                sagg[ct] += e * vfs[ct];
            }
        }
    #pragma unroll
    for (int ct = 0; ct < 4; ++ct) {
        ssum[ct] += __shfl_xor(ssum[ct], 16);
        ssum[ct] += __shfl_xor(ssum[ct], 32);
        sagg[ct] += __shfl_xor(sagg[ct], 16);
        sagg[ct] += __shfl_xor(sagg[ct], 32);
    }
    if (lh == 0) {
        *(f32x4*)&sRedF[512 + w * 64 + 4 * l15]  = (f32x4){ssum[0], ssum[1], ssum[2], ssum[3]};
        *(f32x4*)&sRedF[1024 + w * 64 + 4 * l15] = (f32x4){sagg[0], sagg[1], sagg[2], sagg[3]};
    }
    __syncthreads();
    if (tid < 64) {
        float den = 0.f, ag = 0.f;
        #pragma unroll
        for (int wv = 0; wv < 8; ++wv) {
            den += sRedF[512 + wv * 64 + tid];
            ag  += sRedF[1024 + wv * 64 + tid];
        }
        sRedF[1536 + tid] = ag / den;
    }
    __syncthreads();

    // ---- out[i,:] = x[i,:] + agg @ out_w (threads 0..255) ----
    if (tid < DIMV) {
        float acc = 0.f;
        #pragma unroll 8
        for (int d = 0; d < 64; ++d)
            acc += sRedF[1536 + d] * out_w[d * DIMV + tid];
        const int o = (b * NN + i) * DIMV + tid;
        out[o] = x[o] + acc;
    }
}

// ---------------------------------------------------------------------------
extern "C" void kernel_launch(void* const* d_in, const int* in_sizes, int n_in,
                              void* d_out, int out_size, void* d_ws, size_t ws_size,
                              hipStream_t stream)
{
    const float* x       = (const float*)d_in[0];
    const float* y       = (const float*)d_in[1];
    const float* x_pos   = (const float*)d_in[2];
    const float* y_pos   = (const float*)d_in[3];
    const int*   mask    = (const int*)d_in[4];
    const float* g_w     = (const float*)d_in[5];
    const float* theta_w = (const float*)d_in[6];
    const float* phi_w   = (const float*)d_in[7];
    const float* pos_w1  = (const float*)d_in[8];
    const float* pos_b1  = (const float*)d_in[9];
    const float* pos_w2  = (const float*)d_in[10];
    const float* pos_b2  = (const float*)d_in[11];
    const float* attn_w1 = (const float*)d_in[12];
    const float* attn_b1 = (const float*)d_in[13];
    const float* attn_w2 = (const float*)d_in[14];
    const float* attn_b2 = (const float*)d_in[15];
    const float* out_w   = (const float*)d_in[16];

    float* q = (float*)d_ws;
    float* k = q + NB * NN * DI;
    float* v = k + NB * NN * DI;
    u16* w1t  = (u16*)(v + NB * NN * DI);   // 256*64
    u16* w2t  = w1t + 256 * 64;             // 64*256
    u16* pw2t = w2t + 64 * 256;             // 64*64

    prep_w<<<64, 256, 0, stream>>>(attn_w1, attn_w2, pos_w2, w1t, w2t, pw2t);
    prep_qkv<<<512, 256, 0, stream>>>(x, y, theta_w, phi_w, g_w, q, k, v);
    fused_attn<<<NB * NN, 512, 0, stream>>>(x, x_pos, y_pos, mask,
                                            pos_w1, pos_b1, pos_b2,
                                            attn_b1, attn_b2, out_w,
                                            q, k, v, w1t, w2t, pw2t,
                                            (float*)d_out);
}

// Round 10
// 93.585 us; speedup vs baseline: 2.5545x; 2.2525x over previous
//
#include <hip/hip_runtime.h>
#include <hip/hip_bf16.h>

#define NB 8
#define NN 256
#define DIMV 256
#define DI 64
#define NEGMAX 3.402823466e+38f

typedef unsigned short u16;
typedef unsigned int u32;
typedef __attribute__((ext_vector_type(8))) short bf16x8;
typedef __attribute__((ext_vector_type(4))) float f32x4;
typedef __attribute__((ext_vector_type(2))) float f32x2;
typedef __attribute__((ext_vector_type(2))) unsigned int u32x2;

__device__ __forceinline__ u16 f2bf(float f) {
    __hip_bfloat16 h = __float2bfloat16(f);
    u16 u; __builtin_memcpy(&u, &h, 2); return u;
}
__device__ __forceinline__ u32 pack2(float a, float b) {
    return (u32)f2bf(a) | ((u32)f2bf(b) << 16);
}
__device__ __forceinline__ float ubf_lo(u32 u) {
    union { u32 u; float f; } x; x.u = u << 16; return x.f;
}
__device__ __forceinline__ float ubf_hi(u32 u) {
    union { u32 u; float f; } x; x.u = u & 0xffff0000u; return x.f;
}
// swizzles: fA for 128B-stride rows, fB for 64B-stride rows (bits 4-6 only)
__device__ __forceinline__ int fA(int row) { return ((row & 7) << 4) ^ ((row & 8) << 2); }
__device__ __forceinline__ int fB(int row) { return ((row >> 1) & 7) << 4; }

// ---------------------------------------------------------------------------
// prep: weights -> MFMA-FRAGMENT-MAJOR bf16 layouts.  For each fragment id,
// lane l's 16B chunk lives at (frag*64 + l)*16B -> fused_attn weight loads are
// perfectly coalesced contiguous 1KB/instr (r1-r9 used row gathers: 16B/lane
// from 16-32 distinct rows -> ~8x L2 transaction amplification, the dominant
// per-wave stall at 2 waves/SIMD).
//   w1s[((hc*2+c2)*2+ks)*512 + l*8 + e] = attn_w1[(ks*32+(l>>4)*8+e)*256 + hc*32+2*(l&15)+c2]
//   w2s[(hc*4+ct)*512 + l*8 + e]        = attn_w2[(hc*32+(l>>4)*8+e)*64  + 4*(l&15)+ct]
//   pw2s[(ct*2+ks)*512 + l*8 + e]       = pos_w2 [(ks*32+(l>>4)*8+e)*64  + 4*(l&15)+ct]
// ---------------------------------------------------------------------------
__global__ void prep_w(const float* __restrict__ w1, const float* __restrict__ w2,
                       const float* __restrict__ pw2,
                       u16* __restrict__ w1s, u16* __restrict__ w2s, u16* __restrict__ pw2s)
{
    const int idx = blockIdx.x * 256 + threadIdx.x;   // [0, 16384)
    const int e   = idx & 7;
    const int l   = (idx >> 3) & 63;
    const int l15 = l & 15, lh = l >> 4;
    {   // w1s
        const int frag = idx >> 9;          // 0..31
        const int ks = frag & 1, c2 = (frag >> 1) & 1, hc = frag >> 2;
        w1s[idx] = f2bf(w1[(ks * 32 + lh * 8 + e) * 256 + hc * 32 + 2 * l15 + c2]);
    }
    {   // w2s
        const int frag = idx >> 9;          // 0..31
        const int ct = frag & 3, hc = frag >> 2;
        w2s[idx] = f2bf(w2[(hc * 32 + lh * 8 + e) * 64 + 4 * l15 + ct]);
    }
    if (idx < 4096) {                       // pw2s
        const int frag = idx >> 9;          // 0..7
        const int ks = frag & 1, ct = frag >> 1;
        pw2s[idx] = f2bf(pw2[(ks * 32 + lh * 8 + e) * 64 + 4 * l15 + ct]);
    }
}

// ---------------------------------------------------------------------------
__global__ void prep_qkv(const float* __restrict__ x, const float* __restrict__ y,
                         const float* __restrict__ tw, const float* __restrict__ pw,
                         const float* __restrict__ gw,
                         float* __restrict__ q, float* __restrict__ k, float* __restrict__ v)
{
    __shared__ float xs[4][256];
    __shared__ float ys[4][256];
    const int blk = blockIdx.x;
    const int b = blk >> 6;
    const int n0 = (blk & 63) * 4;
    const int tid = threadIdx.x;
    {
        int r = tid >> 6, e = tid & 63;
        ((float4*)xs[r])[e] = ((const float4*)(x + (size_t)(b * NN + n0 + r) * DIMV))[e];
        ((float4*)ys[r])[e] = ((const float4*)(y + (size_t)(b * NN + n0 + r) * DIMV))[e];
    }
    __syncthreads();
    const int nl = tid >> 6, d = tid & 63;
    float aq = 0.f, ak = 0.f, av = 0.f;
    #pragma unroll 4
    for (int c = 0; c < 256; ++c) {
        float wq = tw[c * 64 + d], wk = pw[c * 64 + d], wv = gw[c * 64 + d];
        float xv = xs[nl][c], yv = ys[nl][c];
        aq += xv * wq; ak += yv * wk; av += yv * wv;
    }
    const int n = n0 + nl;
    q[(b * NN + n) * DI + d] = aq;
    k[(b * NN + n) * DI + d] = ak;
    v[(b * NN + n) * DI + d] = av;
}

// ---------------------------------------------------------------------------
// main fused kernel: one block per (b, i); 4 waves; wave owns rows j0..j0+63.
// Identical structure to r7 (best clean baseline, 110us) except all weight
// loads are fragment-major coalesced (see prep_w).
// ---------------------------------------------------------------------------
__global__ __launch_bounds__(256, 2)
void fused_attn(const float* __restrict__ x, const float* __restrict__ x_pos,
                const float* __restrict__ y_pos, const int* __restrict__ mask,
                const float* __restrict__ pw1, const float* __restrict__ pb1,
                const float* __restrict__ pb2,
                const float* __restrict__ ab1, const float* __restrict__ ab2,
                const float* __restrict__ out_w,
                const float* __restrict__ qg, const float* __restrict__ kg,
                const float* __restrict__ vg,
                const u16* __restrict__ w1s, const u16* __restrict__ w2s,
                const u16* __restrict__ pw2s,
                float* __restrict__ out)
{
    __shared__ __align__(16) char sStg[4][4096];   // 16 KB: stage/Hc per wave
    __shared__ __align__(16) char sV2[4][4096];    // 16 KB: v_full rt 2-3

    const int blk = blockIdx.x;
    const int b = blk >> 8;
    const int i = blk & 255;
    const int tid = threadIdx.x;
    const int l   = tid & 63;
    const int w   = tid >> 6;
    const int j0  = w * 64;
    const int l15 = l & 15;
    const int lh  = l >> 4;

    char* const stg  = sStg[w];
    char* const sV2w = sV2[w];
    float* const sRedF = (float*)&sStg[0][0];      // overlay, post-barrier only

    // hoisted LDS addresses
    int stW[4], hcW[4];
    #pragma unroll
    for (int r = 0; r < 4; ++r) {
        const int lr = lh * 4 + r;
        stW[r] = (lr * 128 + l15 * 8) ^ fA(lr);
        hcW[r] = (lr * 64 + l15 * 4) ^ fB(lr);
    }
    const int stR0 = (l15 * 128 + lh * 16) ^ fA(l15);
    const int stR1 = stR0 ^ 64;
    const int hcR  = (l15 * 64 + lh * 16) ^ fB(l15);

    // ---- mask ----
    const int mjl = mask[b * NN + j0 + l];
    const unsigned long long mb = __ballot(mjl != 0);
    const bool mi_b = mask[b * NN + i] != 0;

    // ---- phase 0: pos-MLP layer 1 into GEMM0 A-fragments ----
    const float xp0 = x_pos[(b * NN + i) * 3 + 0];
    const float xp1 = x_pos[(b * NN + i) * 3 + 1];
    const float xp2 = x_pos[(b * NN + i) * 3 + 2];

    bf16x8 af[4][2];
    {
        float rel[4][3];
        #pragma unroll
        for (int rt = 0; rt < 4; ++rt) {
            const float* yp = y_pos + (size_t)(b * NN + j0 + rt * 16 + l15) * 3;
            rel[rt][0] = xp0 - yp[0];
            rel[rt][1] = xp1 - yp[1];
            rel[rt][2] = xp2 - yp[2];
        }
        #pragma unroll
        for (int ks = 0; ks < 2; ++ks) {
            const int c0 = ks * 32 + lh * 8;
            float w0[8], w1c[8], w2c[8], bb[8];
            #pragma unroll
            for (int qq = 0; qq < 2; ++qq) {
                *(f32x4*)&w0[qq*4]  = *(const f32x4*)&pw1[0*64 + c0 + qq*4];
                *(f32x4*)&w1c[qq*4] = *(const f32x4*)&pw1[1*64 + c0 + qq*4];
                *(f32x4*)&w2c[qq*4] = *(const f32x4*)&pw1[2*64 + c0 + qq*4];
                *(f32x4*)&bb[qq*4]  = *(const f32x4*)&pb1[c0 + qq*4];
            }
            #pragma unroll
            for (int rt = 0; rt < 4; ++rt) {
                bf16x8 v;
                #pragma unroll
                for (int cc = 0; cc < 8; ++cc) {
                    float h = bb[cc] + rel[rt][0]*w0[cc] + rel[rt][1]*w1c[cc] + rel[rt][2]*w2c[cc];
                    v[cc] = (short)f2bf(fmaxf(h, 0.f));
                }
                af[rt][ks] = v;
            }
        }
    }

    // ---- GEMM0 + epilogue per rt; aT hoist; v_full -> accVp (rt<2) / sV2 ----
    const f32x4 qv   = *(const f32x4*)&qg[((size_t)b * NN + i) * DI + 4 * l15];
    const f32x4 pb2v = *(const f32x4*)&pb2[4 * l15];
    bf16x8 bfr[4][2];
    #pragma unroll
    for (int ct = 0; ct < 4; ++ct)
        #pragma unroll
        for (int ks = 0; ks < 2; ++ks)
            bfr[ct][ks] = *(const bf16x8*)(pw2s + ((ct * 2 + ks) * 64 + l) * 8);

    bf16x8 aT[4][2];
    u32x2 accVp[2][4];
    #pragma unroll
    for (int rt = 0; rt < 4; ++rt) {
        f32x4 accR[4];
        #pragma unroll
        for (int ct = 0; ct < 4; ++ct) {
            f32x4 a = {pb2v[ct], pb2v[ct], pb2v[ct], pb2v[ct]};   // pb2 folded
            a = __builtin_amdgcn_mfma_f32_16x16x32_bf16(af[rt][0], bfr[ct][0], a, 0, 0, 0);
            a = __builtin_amdgcn_mfma_f32_16x16x32_bf16(af[rt][1], bfr[ct][1], a, 0, 0, 0);
            accR[ct] = a;
        }
        #pragma unroll
        for (int r = 0; r < 4; ++r) {
            const int row = j0 + rt * 16 + lh * 4 + r;
            const f32x4 kv = *(const f32x4*)&kg[((size_t)b * NN + row) * DI + 4 * l15];
            const f32x4 vv = *(const f32x4*)&vg[((size_t)b * NN + row) * DI + 4 * l15];
            float tv[4], vf[4];
            #pragma unroll
            for (int ct = 0; ct < 4; ++ct) {
                const float rpe = accR[ct][r];
                tv[ct] = qv[ct] - kv[ct] + rpe;
                vf[ct] = vv[ct] + rpe;
            }
            u32x2 tpk; tpk[0] = pack2(tv[0], tv[1]); tpk[1] = pack2(tv[2], tv[3]);
            u32x2 vpk; vpk[0] = pack2(vf[0], vf[1]); vpk[1] = pack2(vf[2], vf[3]);
            *(u32x2*)(stg + stW[r]) = tpk;
            if (rt < 2) accVp[rt][r] = vpk;
            else        *(u32x2*)(sV2w + stW[r] + (rt - 2) * 2048) = vpk;
        }
        aT[rt][0] = *(const bf16x8*)(stg + stR0);
        aT[rt][1] = *(const bf16x8*)(stg + stR1);
    }

    // ---- chunk loop: 8 chunks of 32 hidden; SIM accumulates in regs ----
    const f32x4 ab2v = *(const f32x4*)&ab2[4 * l15];
    f32x4 accS[4][4];
    #pragma unroll
    for (int rt = 0; rt < 4; ++rt)
        #pragma unroll
        for (int ct = 0; ct < 4; ++ct)
            accS[rt][ct] = (f32x4){ab2v[ct], ab2v[ct], ab2v[ct], ab2v[ct]};  // ab2 folded

    #pragma unroll 2
    for (int hc = 0; hc < 8; ++hc) {
        bf16x8 b1f[2][2];
        #pragma unroll
        for (int c2 = 0; c2 < 2; ++c2)
            #pragma unroll
            for (int ks = 0; ks < 2; ++ks)
                b1f[c2][ks] = *(const bf16x8*)(w1s + ((hc * 4 + c2 * 2 + ks) * 64 + l) * 8);
        bf16x8 b2f[4];
        #pragma unroll
        for (int ct = 0; ct < 4; ++ct)
            b2f[ct] = *(const bf16x8*)(w2s + ((hc * 4 + ct) * 64 + l) * 8);
        const f32x2 ab1v = *(const f32x2*)&ab1[hc * 32 + 2 * l15];
        const f32x4 ib0 = {ab1v[0], ab1v[0], ab1v[0], ab1v[0]};
        const f32x4 ib1 = {ab1v[1], ab1v[1], ab1v[1], ab1v[1]};
        #pragma unroll
        for (int rt = 0; rt < 4; ++rt) {
            f32x4 h0 = ib0, h1 = ib1;                  // ab1 folded
            h0 = __builtin_amdgcn_mfma_f32_16x16x32_bf16(aT[rt][0], b1f[0][0], h0, 0, 0, 0);
            h0 = __builtin_amdgcn_mfma_f32_16x16x32_bf16(aT[rt][1], b1f[0][1], h0, 0, 0, 0);
            h1 = __builtin_amdgcn_mfma_f32_16x16x32_bf16(aT[rt][0], b1f[1][0], h1, 0, 0, 0);
            h1 = __builtin_amdgcn_mfma_f32_16x16x32_bf16(aT[rt][1], b1f[1][1], h1, 0, 0, 0);
            #pragma unroll
            for (int r = 0; r < 4; ++r)
                *(u32*)(stg + hcW[r] + rt * 1024) =
                    pack2(fmaxf(h0[r], 0.f), fmaxf(h1[r], 0.f));
        }
        #pragma unroll
        for (int rt = 0; rt < 4; ++rt) {
            bf16x8 a2 = *(const bf16x8*)(stg + hcR + rt * 1024);
            #pragma unroll
            for (int ct = 0; ct < 4; ++ct)
                accS[rt][ct] = __builtin_amdgcn_mfma_f32_16x16x32_bf16(a2, b2f[ct], accS[rt][ct], 0, 0, 0);
        }
    }

    // ---- softmax: in-register over accS; cross-lane + cross-wave ----
    float mx[4] = {-NEGMAX, -NEGMAX, -NEGMAX, -NEGMAX};
    #pragma unroll
    for (int rt = 0; rt < 4; ++rt)
        #pragma unroll
        for (int r = 0; r < 4; ++r) {
            const int ro = rt * 16 + lh * 4 + r;
            const bool bit = mi_b && ((mb >> ro) & 1ull);
            #pragma unroll
            for (int ct = 0; ct < 4; ++ct) {
                float s = bit ? accS[rt][ct][r] : -NEGMAX;
                accS[rt][ct][r] = s;
                mx[ct] = fmaxf(mx[ct], s);
            }
        }
    #pragma unroll
    for (int ct = 0; ct < 4; ++ct) {
        mx[ct] = fmaxf(mx[ct], __shfl_xor(mx[ct], 16));
        mx[ct] = fmaxf(mx[ct], __shfl_xor(mx[ct], 32));
    }
    __syncthreads();                    // Hc/stage regions dead -> sRed overlay OK
    if (lh == 0)
        *(f32x4*)&sRedF[w * 64 + 4 * l15] = (f32x4){mx[0], mx[1], mx[2], mx[3]};
    __syncthreads();
    float m4[4];
    {
        f32x4 a0 = *(f32x4*)&sRedF[      4 * l15];
        f32x4 a1 = *(f32x4*)&sRedF[ 64 + 4 * l15];
        f32x4 a2 = *(f32x4*)&sRedF[128 + 4 * l15];
        f32x4 a3 = *(f32x4*)&sRedF[192 + 4 * l15];
        #pragma unroll
        for (int ct = 0; ct < 4; ++ct)
            m4[ct] = fmaxf(fmaxf(a0[ct], a1[ct]), fmaxf(a2[ct], a3[ct]));
    }
    float ssum[4] = {0.f, 0.f, 0.f, 0.f}, sagg[4] = {0.f, 0.f, 0.f, 0.f};
    #pragma unroll
    for (int rt = 0; rt < 4; ++rt)
        #pragma unroll
        for (int r = 0; r < 4; ++r) {
            u32x2 vpk;
            if (rt < 2) vpk = accVp[rt][r];
            else        vpk = *(const u32x2*)(sV2w + stW[r] + (rt - 2) * 2048);
            const float vfs[4] = {ubf_lo(vpk[0]), ubf_hi(vpk[0]), ubf_lo(vpk[1]), ubf_hi(vpk[1])};
            #pragma unroll
            for (int ct = 0; ct < 4; ++ct) {
                const float e = __expf(accS[rt][ct][r] - m4[ct]);
                ssum[ct] += e;
                sagg[ct] += e * vfs[ct];
            }
        }
    #pragma unroll
    for (int ct = 0; ct < 4; ++ct) {
        ssum[ct] += __shfl_xor(ssum[ct], 16);
        ssum[ct] += __shfl_xor(ssum[ct], 32);
        sagg[ct] += __shfl_xor(sagg[ct], 16);
        sagg[ct] += __shfl_xor(sagg[ct], 32);
    }
    if (lh == 0) {
        *(f32x4*)&sRedF[256 + w * 64 + 4 * l15] = (f32x4){ssum[0], ssum[1], ssum[2], ssum[3]};
        *(f32x4*)&sRedF[512 + w * 64 + 4 * l15] = (f32x4){sagg[0], sagg[1], sagg[2], sagg[3]};
    }
    __syncthreads();
    if (tid < 64) {
        float den = sRedF[256 + tid] + sRedF[320 + tid] + sRedF[384 + tid] + sRedF[448 + tid];
        float ag  = sRedF[512 + tid] + sRedF[576 + tid] + sRedF[640 + tid] + sRedF[704 + tid];
        sRedF[768 + tid] = ag / den;
    }
    __syncthreads();

    // ---- out[i,:] = x[i,:] + agg @ out_w ----
    {
        float acc = 0.f;
        #pragma unroll 8
        for (int d = 0; d < 64; ++d)
            acc += sRedF[768 + d] * out_w[d * DIMV + tid];
        const int o = (b * NN + i) * DIMV + tid;
        out[o] = x[o] + acc;
    }
}

// ---------------------------------------------------------------------------
extern "C" void kernel_launch(void* const* d_in, const int* in_sizes, int n_in,
                              void* d_out, int out_size, void* d_ws, size_t ws_size,
                              hipStream_t stream)
{
    const float* x       = (const float*)d_in[0];
    const float* y       = (const float*)d_in[1];
    const float* x_pos   = (const float*)d_in[2];
    const float* y_pos   = (const float*)d_in[3];
    const int*   mask    = (const int*)d_in[4];
    const float* g_w     = (const float*)d_in[5];
    const float* theta_w = (const float*)d_in[6];
    const float* phi_w   = (const float*)d_in[7];
    const float* pos_w1  = (const float*)d_in[8];
    const float* pos_b1  = (const float*)d_in[9];
    const float* pos_w2  = (const float*)d_in[10];
    const float* pos_b2  = (const float*)d_in[11];
    const float* attn_w1 = (const float*)d_in[12];
    const float* attn_b1 = (const float*)d_in[13];
    const float* attn_w2 = (const float*)d_in[14];
    const float* attn_b2 = (const float*)d_in[15];
    const float* out_w   = (const float*)d_in[16];

    float* q = (float*)d_ws;
    float* k = q + NB * NN * DI;
    float* v = k + NB * NN * DI;
    u16* w1s  = (u16*)(v + NB * NN * DI);   // 16384 u16 (fragment-major)
    u16* w2s  = w1s + 16384;                // 16384 u16
    u16* pw2s = w2s + 16384;                // 4096 u16

    prep_w<<<64, 256, 0, stream>>>(attn_w1, attn_w2, pos_w2, w1s, w2s, pw2s);
    prep_qkv<<<512, 256, 0, stream>>>(x, y, theta_w, phi_w, g_w, q, k, v);
    fused_attn<<<NB * NN, 256, 0, stream>>>(x, x_pos, y_pos, mask,
                                            pos_w1, pos_b1, pos_b2,
                                            attn_b1, attn_b2, out_w,
                                            q, k, v, w1s, w2s, pw2s,
                                            (float*)d_out);
}